// Round 9
// baseline (207.581 us; speedup 1.0000x reference)
//
#include <hip/hip_runtime.h>
#include <hip/hip_bf16.h>

// Problem dims (fixed by reference): E=8, D=2048, B=4096, 3 layers.
#define MDIM 4096
#define NDIM 2048
#define KDIM 2048
#define KTILES 32          // K / 64
#define PER_LAYER 4194304  // 2048*2048

typedef __attribute__((ext_vector_type(8))) short bf16x8;   // 8 bf16 (4 VGPRs)
typedef __attribute__((ext_vector_type(4))) float f32x4;    // MFMA accumulator

__device__ __forceinline__ unsigned short f2bf(float f) {
    unsigned u = __builtin_bit_cast(unsigned, f);
    u += 0x7FFFu + ((u >> 16) & 1u);        // round-to-nearest-even
    return (unsigned short)(u >> 16);
}

// ---------------------------------------------------------------------------
// Kernel 1: blend layer-0 experts + convert x to bf16 (W1/W2 blend is fused
// into the GEMM kernels). Reads 134MB W0 + 32MB x -> ~30us HBM-bound.
// ---------------------------------------------------------------------------
__global__ __launch_bounds__(256) void blend0_kernel(
    const float* __restrict__ W, const float* __restrict__ cb,
    const float* __restrict__ x,
    unsigned short* __restrict__ wb, unsigned short* __restrict__ xb)
{
    float c[8];
#pragma unroll
    for (int e = 0; e < 8; ++e) c[e] = cb[e];
    const unsigned wtotal4 = PER_LAYER >> 2;        // 1,048,576 float4 units
    const unsigned xtotal4 = 2097152u;              // 8M / 4
    const unsigned total = wtotal4 + xtotal4;
    unsigned stride = gridDim.x * blockDim.x;
    for (unsigned i = blockIdx.x * blockDim.x + threadIdx.x; i < total; i += stride) {
        if (i < wtotal4) {
            unsigned off = i << 2;
            const float* base = W + off;
            float4 s = make_float4(0.f, 0.f, 0.f, 0.f);
#pragma unroll
            for (int e = 0; e < 8; ++e) {
                float4 v = *(const float4*)(base + (size_t)e * PER_LAYER);
                s.x += c[e] * v.x; s.y += c[e] * v.y;
                s.z += c[e] * v.z; s.w += c[e] * v.w;
            }
            ushort4 o;
            o.x = f2bf(s.x); o.y = f2bf(s.y); o.z = f2bf(s.z); o.w = f2bf(s.w);
            *(ushort4*)(wb + off) = o;
        } else {
            unsigned j = (i - wtotal4) << 2;
            float4 v = *(const float4*)(x + j);
            ushort4 o;
            o.x = f2bf(v.x); o.y = f2bf(v.y); o.z = f2bf(v.z); o.w = f2bf(v.w);
            *(ushort4*)(xb + j) = o;
        }
    }
}

// ---------------------------------------------------------------------------
// Kernel 2: 256x128 bf16 GEMM, 3-buf LDS (144KB), 2-tile-deep prefetch,
// FOUR m201-style phases per K-tile (quadrant walk, B0 regs held P1->P4),
// counted vmcnt once per K-tile; fused next-layer blend (r7 ledger).
//   C[M,N] = A[M,K] * Bw[N,K]^T + bias, optional ELU;  wbNext = sum_e c_e W_e.
// grid = 256 blocks (all CUs), 512 threads = 8 waves (4M x 2N), wave 64x64.
// Phase p: {ds_read quadrant; 2x stage(t+2); barrier; lgkmcnt(0); setprio(1);
//           8 MFMA; setprio(0); barrier}   (P4: no reads, vmcnt before barrier)
//   P1: read A0(m0,1),B0(n0,1) -> MFMA A0xB0 ; stage A-slab0,1
//   P2: read B1(n2,3)          -> MFMA A0xB1 ; stage A-slab2,3
//   P3: read A1(m2,3)          -> MFMA A1xB1 ; stage B-slab0,1
//   P4: (regs only)            -> MFMA A1xB0 ; VMC; barrier
// vmcnt ledger: end-of-t outstanding = S(t+1)6 + S(t+2)6 -> VMC(6);
// blend iter u (9 ops at start): -> VMC(15) at end-of-u (r7-verified).
// WAR: stage target (t+2)%3 last read iter t-1 (reads complete before that
// iter's end barrier via lgkm-before-MFMA). RAW: VMC + end barrier.
// ---------------------------------------------------------------------------
#define BARR() do { asm volatile("" ::: "memory"); __builtin_amdgcn_s_barrier(); asm volatile("" ::: "memory"); } while (0)
#define SP(N) __builtin_amdgcn_s_setprio(N)
#define LGKM0() asm volatile("s_waitcnt lgkmcnt(0)" ::: "memory")
#define VMC_IMPL(N) asm volatile("s_waitcnt vmcnt(" #N ")" ::: "memory")
#define VMC(N) VMC_IMPL(N)

template<int ACT, typename OutT, int BLEND>
__global__ __launch_bounds__(512, 2) void gemm_fused(
    const unsigned short* __restrict__ A,   // M x K bf16 bits
    const unsigned short* __restrict__ Bw,  // N x K bf16 bits
    const float* __restrict__ bias,         // N
    OutT* __restrict__ C,                   // M x N
    const float* __restrict__ Wnext,        // 8 x 2048 x 2048 f32 (or null)
    const float* __restrict__ cb,           // (8,) blend coeffs (or null)
    unsigned short* __restrict__ wbNext)    // 2048 x 2048 bf16 out (or null)
{
    __shared__ __align__(16) unsigned short lds[73728];   // 144 KB
    char* ldsc = (char*)lds;

    const int tid = threadIdx.x;
    const int wid = tid >> 6;
    const int lane = tid & 63;
    const int wr = wid >> 1;      // 0..3 (M)
    const int wc = wid & 1;       // 0..1 (N)

    // blend coeffs: load + fence BEFORE any counted vmem ops.
    float cw[8];
    if (BLEND) {
#pragma unroll
        for (int e = 0; e < 8; ++e) cw[e] = cb[e];
        VMC(0);
    }

    // bijective XCD-chunked swizzle: XCD k gets wg in [k*32,(k+1)*32)
    // = 2 N-panels x 16 M-tiles -> B panels (1MB) L2-resident per XCD.
    const int wg = (blockIdx.x & 7) * 32 + (blockIdx.x >> 3);
    const size_t blockM = (size_t)(wg & 15) * 256;
    const size_t blockN = (size_t)(wg >> 4) * 128;

    // ds_read addressing: swizzled 16B slot within a 128B row.
    const int sw = (lane & 7) << 4;          // (row&7)<<4; row&7 == lane&7
    const int ck = (lane >> 4) << 4;         // k-slot byte base
    const int rAb = wr * 64 + (lane & 15);   // + m*16
    const int rBb = wc * 64 + (lane & 15);   // + n*16

    // staging: thread t writes LDS bytes [tid*16, tid*16+16) of an 8KB
    // 64-row stage; source column pre-XORed (both-sides swizzle).
    const int srow = tid >> 3;                       // 0..63
    const int scol = ((tid & 7) ^ (srow & 7)) << 3;  // element offset
    const unsigned short* aStage = A + (blockM + srow) * KDIM + scol;
    const unsigned short* bStage = Bw + (blockN + srow) * KDIM + scol;

#define STAGE_AS(BUF, S, KT) do { \
    const unsigned short* g_ = aStage + (size_t)(S) * 64 * KDIM + (size_t)(KT) * 64; \
    __builtin_amdgcn_global_load_lds((const __attribute__((address_space(1))) void*)g_, \
        (__attribute__((address_space(3))) void*)(ldsc + (BUF) * 49152 + (S) * 8192 + tid * 16), \
        16, 0, 0); \
} while (0)

#define STAGE_BS(BUF, S, KT) do { \
    const unsigned short* g_ = bStage + (size_t)(S) * 64 * KDIM + (size_t)(KT) * 64; \
    __builtin_amdgcn_global_load_lds((const __attribute__((address_space(1))) void*)g_, \
        (__attribute__((address_space(3))) void*)(ldsc + (BUF) * 49152 + 32768 + (S) * 8192 + tid * 16), \
        16, 0, 0); \
} while (0)

#define RD_A(BUF, M, KK) \
    (*(const bf16x8*)(ldsc + (BUF) * 49152 + ((rAb + (M) * 16)) * 128 + (((KK) * 64 + ck) ^ sw)))
#define RD_B(BUF, N, KK) \
    (*(const bf16x8*)(ldsc + (BUF) * 49152 + 32768 + (rBb + (N) * 16) * 128 + (((KK) * 64 + ck) ^ sw)))

// read one quadrant (2 frag rows x 2 k-halves) into named regs
#define READ_AQ(DST, BUF, MB) do { \
    DST[0][0] = RD_A(BUF, (MB) + 0, 0); DST[0][1] = RD_A(BUF, (MB) + 0, 1); \
    DST[1][0] = RD_A(BUF, (MB) + 1, 0); DST[1][1] = RD_A(BUF, (MB) + 1, 1); } while (0)
#define READ_BQ(DST, BUF, NB) do { \
    DST[0][0] = RD_B(BUF, (NB) + 0, 0); DST[0][1] = RD_B(BUF, (NB) + 0, 1); \
    DST[1][0] = RD_B(BUF, (NB) + 1, 0); DST[1][1] = RD_B(BUF, (NB) + 1, 1); } while (0)
// 8 MFMA: quadrant (MB..MB+1) x (NB..NB+1) over both k-halves
#define MFQ(AQ, BQ, MB, NB) do { \
    _Pragma("unroll") for (int kk_ = 0; kk_ < 2; ++kk_) \
    _Pragma("unroll") for (int mi_ = 0; mi_ < 2; ++mi_) \
    _Pragma("unroll") for (int ni_ = 0; ni_ < 2; ++ni_) \
        acc[(MB) + mi_][(NB) + ni_] = __builtin_amdgcn_mfma_f32_16x16x32_bf16( \
            AQ[mi_][kk_], BQ[ni_][kk_], acc[(MB) + mi_][(NB) + ni_], 0, 0, 0); } while (0)

    f32x4 acc[4][4];
#pragma unroll
    for (int m = 0; m < 4; ++m)
#pragma unroll
        for (int n = 0; n < 4; ++n) acc[m][n] = (f32x4){0.f, 0.f, 0.f, 0.f};

    // one blend chunk: thread blends float4 #(G*131072 + bid*512 + tid)
#define BLEND_STEP(G) do { \
    const unsigned idx_ = (unsigned)(G) * 131072u + (unsigned)blockIdx.x * 512u + (unsigned)tid; \
    const unsigned off_ = idx_ << 2; \
    const float* bs_ = Wnext + off_; \
    float4 s_ = make_float4(0.f, 0.f, 0.f, 0.f); \
    _Pragma("unroll") for (int e_ = 0; e_ < 8; ++e_) { \
        float4 v_ = *(const float4*)(bs_ + (size_t)e_ * PER_LAYER); \
        s_.x += cw[e_] * v_.x; s_.y += cw[e_] * v_.y; \
        s_.z += cw[e_] * v_.z; s_.w += cw[e_] * v_.w; } \
    ushort4 o_; \
    o_.x = f2bf(s_.x); o_.y = f2bf(s_.y); o_.z = f2bf(s_.z); o_.w = f2bf(s_.w); \
    *(ushort4*)(wbNext + off_) = o_; \
} while (0)

    // One K-tile: 4 phases (see header comment). WAITER placed after P4 MFMA.
#define GEMM_ITER(T, WAITER) do { \
    int stb_ = cur + 2; if (stb_ >= 3) stb_ -= 3; \
    bf16x8 a0_[2][2], a1_[2][2], b0_[2][2], b1_[2][2]; \
    /* P1 */ \
    READ_AQ(a0_, cur, 0); READ_BQ(b0_, cur, 0); \
    if ((T) + 2 < KTILES) { STAGE_AS(stb_, 0, (T) + 2); STAGE_AS(stb_, 1, (T) + 2); } \
    BARR(); LGKM0(); SP(1); MFQ(a0_, b0_, 0, 0); SP(0); BARR(); \
    /* P2 */ \
    READ_BQ(b1_, cur, 2); \
    if ((T) + 2 < KTILES) { STAGE_AS(stb_, 2, (T) + 2); STAGE_AS(stb_, 3, (T) + 2); } \
    BARR(); LGKM0(); SP(1); MFQ(a0_, b1_, 0, 2); SP(0); BARR(); \
    /* P3 */ \
    READ_AQ(a1_, cur, 2); \
    if ((T) + 2 < KTILES) { STAGE_BS(stb_, 0, (T) + 2); STAGE_BS(stb_, 1, (T) + 2); } \
    BARR(); LGKM0(); SP(1); MFQ(a1_, b1_, 2, 2); SP(0); BARR(); \
    /* P4: register-only */ \
    SP(1); MFQ(a1_, b0_, 2, 0); SP(0); \
    WAITER; \
    BARR(); \
    cur = cur + 1; if (cur >= 3) cur = 0; \
} while (0)

    // ---- prologue: tile0 -> buf0, tile1 -> buf1 ----
    STAGE_AS(0, 0, 0); STAGE_AS(0, 1, 0); STAGE_AS(0, 2, 0); STAGE_AS(0, 3, 0);
    STAGE_BS(0, 0, 0); STAGE_BS(0, 1, 0);
    STAGE_AS(1, 0, 1); STAGE_AS(1, 1, 1); STAGE_AS(1, 2, 1); STAGE_AS(1, 3, 1);
    STAGE_BS(1, 0, 1); STAGE_BS(1, 1, 1);
    VMC(6);                       // tile0 landed; tile1's 6 in flight
    BARR();

    int cur = 0;
    if (BLEND) {
#pragma unroll 1
        for (int g = 0; g < 8; ++g) {
            GEMM_ITER(3 * g, VMC(6));
            BLEND_STEP(g);                     // 9 vmem ops at start of iter 3g+1
            GEMM_ITER(3 * g + 1, VMC(15));     // drain S(3g+2); keep blend+S(3g+3)
            GEMM_ITER(3 * g + 2, VMC(6));      // drains blend + S(3g+3)
        }
#pragma unroll 1
        for (int t = 24; t < 30; ++t) GEMM_ITER(t, VMC(6));
    } else {
#pragma unroll 1
        for (int t = 0; t < 30; ++t) GEMM_ITER(t, VMC(6));
    }
    GEMM_ITER(30, VMC(0));        // stages nothing; drains S(31)
    GEMM_ITER(31, VMC(0));        // final tile

    // ---- epilogue: C/D layout col=lane&15 (N), row=(lane>>4)*4+reg (M) ----
    const int crow = (lane >> 4) * 4;
    const int ccol = lane & 15;
#pragma unroll
    for (int m = 0; m < 4; ++m)
#pragma unroll
        for (int n = 0; n < 4; ++n) {
            const size_t col = blockN + wc * 64 + n * 16 + ccol;
            const float bv = bias[col];
#pragma unroll
            for (int r = 0; r < 4; ++r) {
                const size_t row = blockM + wr * 64 + m * 16 + crow + r;
                float v = acc[m][n][r] + bv;
                if (ACT) v = v > 0.f ? v : expm1f(v);
                if constexpr (sizeof(OutT) == 2) {
                    C[row * NDIM + col] = (OutT)f2bf(v);
                } else {
                    C[row * NDIM + col] = (OutT)v;
                }
            }
        }
#undef STAGE_AS
#undef STAGE_BS
#undef RD_A
#undef RD_B
#undef READ_AQ
#undef READ_BQ
#undef MFQ
#undef GEMM_ITER
#undef BLEND_STEP
}

// ---------------------------------------------------------------------------
// Launch: blend0+convert, then 3 chained GEMMs; GEMM0 blends W1, GEMM1
// blends W2 (overlapped with compute), GEMM2 plain.
// Workspace (ushort units): wb[3*PER_LAYER] weights, xb[8388608], y0[8388608].
// ---------------------------------------------------------------------------
extern "C" void kernel_launch(void* const* d_in, const int* in_sizes, int n_in,
                              void* d_out, int out_size, void* d_ws, size_t ws_size,
                              hipStream_t stream) {
    const float* blendw = (const float*)d_in[0];   // (8,)
    const float* x      = (const float*)d_in[1];   // (4096, 2048)
    const float* W      = (const float*)d_in[2];   // (3, 8, 2048, 2048)
    const float* Bb     = (const float*)d_in[3];   // (3, 2048)
    float* out = (float*)d_out;                    // (4096, 2048) f32

    unsigned short* wb0 = (unsigned short*)d_ws;
    unsigned short* wb1 = wb0 + PER_LAYER;
    unsigned short* wb2 = wb1 + PER_LAYER;
    unsigned short* xb  = wb2 + PER_LAYER;
    unsigned short* y0  = xb + 8388608;
    unsigned short* y1  = xb;   // reuse: xb dead after GEMM0

    blend0_kernel<<<2048, 256, 0, stream>>>(W, blendw, x, wb0, xb);

    const int grid = (MDIM / 256) * (NDIM / 128);    // 256 blocks = all CUs
    gemm_fused<1, unsigned short, 1><<<grid, 512, 0, stream>>>(
        xb, wb0, Bb,        y0,  W + (size_t)8 * PER_LAYER,  blendw, wb1);
    gemm_fused<1, unsigned short, 1><<<grid, 512, 0, stream>>>(
        y0, wb1, Bb + 2048, y1,  W + (size_t)16 * PER_LAYER, blendw, wb2);
    gemm_fused<0, float, 0><<<grid, 512, 0, stream>>>(
        y1, wb2, Bb + 4096, out, nullptr, nullptr, nullptr);
}